// Round 8
// baseline (981.919 us; speedup 1.0000x reference)
//
#include <hip/hip_runtime.h>

#define N_NODES 100000
#define N_EDGES 1600000

// ---------------- workspace layout (floats) ----------------
// 0    : s      (N)   softmax denom
// N    : hagg1  (8N)
// 9N   : agg1   (N)
// 10N  : agg2   (N)
// 11N  : hagg2  (8N)
// 19N  : h_enc  (8N)
// 27N  : h_r1   (8N)
// 35N  : h_r2   (8N)
// 43N  : wbuf   (E)
// +E   : he1    (E)
// +E   : he2    (E)
// +E   : packed weights

__global__ void zero_kernel(float* p, int n) {
    int i = blockIdx.x * blockDim.x + threadIdx.x;
    int stride = gridDim.x * blockDim.x;
    for (; i < n; i += stride) p[i] = 0.f;
}

// exp(d) directly: edge_dist ~ N(0,1), max ~5 -> exp <= ~150, no overflow.
// softmax identical up to ulp: exp(d)/sum(exp(d)) == exp(d-m)/sum(exp(d-m)).
__global__ void exp_sum_kernel(const float* __restrict__ dist, const int* __restrict__ dst,
                               float* __restrict__ s, float* __restrict__ wbuf, int E) {
    int e = blockIdx.x * blockDim.x + threadIdx.x;
    if (e >= E) return;
    float v = expf(dist[e]);
    wbuf[e] = v;
    atomicAdd(s + dst[e], v);
}

// one thread per (edge, channel); 8 channels
template <bool NORM>
__global__ void agg_kernel(float* wbuf, const float* __restrict__ s,
                           const float* __restrict__ hfeat,
                           const int* __restrict__ src, const int* __restrict__ dst,
                           float* __restrict__ out, int E) {
    int t = blockIdx.x * blockDim.x + threadIdx.x;
    if (t >= E * 8) return;
    int e = t >> 3, c = t & 7;
    float w = wbuf[e];
    int d = dst[e];
    if (NORM) {
        w = w / s[d];
        // all 8 lanes of this edge-group read wbuf[e] in lockstep (same wave)
        // before this store executes, so in-place normalize is safe.
        if (c == 0) wbuf[e] = w;
    }
    atomicAdd(out + d * 8 + c, w * hfeat[src[e] * 8 + c]);
}

// ---------------- weight packing -------------------------------------------
// Per-k row (k = hidden-1 unit): [0..63] = w2[k,:]
//                                [64..64+DIN-1] = w1[:,k] (column)
//                                [64+DIN] = b1[k]
struct PackArgs { const float *w1, *b1, *w2; float* out; int din, stride; };

__global__ void pack_kernel(PackArgs a0, PackArgs a1, PackArgs a2, PackArgs a3) {
    PackArgs a = (blockIdx.x == 0) ? a0 : (blockIdx.x == 1) ? a1
               : (blockIdx.x == 2) ? a2 : a3;
    int k = threadIdx.x;  // 64 threads
    float* row = a.out + k * a.stride;
    for (int j = 0; j < 64; ++j) row[j] = a.w2[k * 64 + j];
    for (int j = 0; j < a.din; ++j) row[64 + j] = a.w1[j * 64 + k];
    row[64 + a.din] = a.b1[k];
}

// ---------------- LDS weight staging ---------------------------------------
// One coalesced copy per block; all lanes then read the same row address per
// k-iteration -> pure broadcast, zero bank conflicts, ds_read_b128 ops on the
// LDS pipe instead of per-iteration VMEM/SMEM traffic.
template <int WORDS>
__device__ __forceinline__ void stage_weights(float* wlds, const float* __restrict__ wp) {
    for (int i = threadIdx.x; i < WORDS / 4; i += 256)
        ((float4*)wlds)[i] = ((const float4*)wp)[i];
    __syncthreads();
}

// ---------------- loop-swapped fused MLP: DIN -> 64 -> 64 -> DOUT ----------
// Weights come from LDS (wlds). Explicit float4 reads -> ds_read_b128.
// Accumulation order identical to reference (k ascending, j ascending).
template <int DIN, int DOUT, int STRIDE>
__device__ __forceinline__ void mlp_fused(
    const float* __restrict__ x, const float* wlds,
    const float* __restrict__ b2,
    const float* __restrict__ w3, const float* __restrict__ b3,
    float* __restrict__ out) {
    float h2[64];
#pragma unroll
    for (int j = 0; j < 64; ++j) h2[j] = b2[j];
    for (int k = 0; k < 64; ++k) {
        const float* row = wlds + k * STRIDE;
        float a = row[64 + DIN];
#pragma unroll
        for (int j = 0; j < DIN; ++j) a = fmaf(x[j], row[64 + j], a);
        a = fmaxf(a, 0.f);
#pragma unroll
        for (int j4 = 0; j4 < 16; ++j4) {
            float4 w4 = *(const float4*)(row + 4 * j4);
            h2[4 * j4 + 0] = fmaf(a, w4.x, h2[4 * j4 + 0]);
            h2[4 * j4 + 1] = fmaf(a, w4.y, h2[4 * j4 + 1]);
            h2[4 * j4 + 2] = fmaf(a, w4.z, h2[4 * j4 + 2]);
            h2[4 * j4 + 3] = fmaf(a, w4.w, h2[4 * j4 + 3]);
        }
    }
    float acc[DOUT];
#pragma unroll
    for (int o = 0; o < DOUT; ++o) acc[o] = b3[o];
#pragma unroll
    for (int j = 0; j < 64; ++j) {
        float r = fmaxf(h2[j], 0.f);
#pragma unroll
        for (int o = 0; o < DOUT; ++o) acc[o] = fmaf(r, w3[j * DOUT + o], acc[o]);
    }
#pragma unroll
    for (int o = 0; o < DOUT; ++o) out[o] = fmaxf(acc[o], 0.f);
}

// thread-per-node MLP: x = concat(xa[CA], xb[CB]) -> DOUT
template <int CA, int CB, int DOUT, int STRIDE>
__global__ __launch_bounds__(256, 3) void node_mlp_kernel(
    const float* __restrict__ xa, const float* __restrict__ xb,
    const float* __restrict__ wp, const float* __restrict__ b2,
    const float* __restrict__ w3, const float* __restrict__ b3,
    float* __restrict__ out, int n) {
    constexpr int DIN = CA + CB;
    __shared__ float wlds[STRIDE * 64];
    stage_weights<STRIDE * 64>(wlds, wp);
    int i = blockIdx.x * 256 + threadIdx.x;
    if (i >= n) return;
    float x[DIN];
#pragma unroll
    for (int k = 0; k < CA; ++k) x[k] = xa[i * CA + k];
    if (CB == 8) {
        float4 v0 = *(const float4*)(xb + i * 8);
        float4 v1 = *(const float4*)(xb + i * 8 + 4);
        x[CA + 0] = v0.x; x[CA + 1] = v0.y; x[CA + 2] = v0.z; x[CA + 3] = v0.w;
        x[CA + 4] = v1.x; x[CA + 5] = v1.y; x[CA + 6] = v1.z; x[CA + 7] = v1.w;
    }
    float o[DOUT];
    mlp_fused<DIN, DOUT, STRIDE>(x, wlds, b2, w3, b3, o);
#pragma unroll
    for (int k = 0; k < DOUT; ++k) out[i * DOUT + k] = o[k];
}

// thread-per-edge MLP: 17 -> 64 -> 64 -> 1, plus segment-sum into agg[dst]
__global__ __launch_bounds__(256, 3) void edge_mlp_kernel(
    const float* __restrict__ he_in, const float* __restrict__ h,
    const int* __restrict__ src, const int* __restrict__ dst,
    const float* __restrict__ wp, const float* __restrict__ b2,
    const float* __restrict__ w3, const float* __restrict__ b3,
    float* __restrict__ he_out, float* __restrict__ agg, int E) {
    __shared__ float wlds[96 * 64];
    stage_weights<96 * 64>(wlds, wp);
    int e = blockIdx.x * 256 + threadIdx.x;
    if (e >= E) return;
    int d = dst[e], sr = src[e];
    float x[17];
    x[0] = he_in[e];
    float4 a0 = *(const float4*)(h + sr * 8);
    float4 a1 = *(const float4*)(h + sr * 8 + 4);
    float4 d0 = *(const float4*)(h + d * 8);
    float4 d1 = *(const float4*)(h + d * 8 + 4);
    x[1] = a0.x;  x[2] = a0.y;  x[3] = a0.z;  x[4] = a0.w;
    x[5] = a1.x;  x[6] = a1.y;  x[7] = a1.z;  x[8] = a1.w;
    x[9] = d0.x;  x[10] = d0.y; x[11] = d0.z; x[12] = d0.w;
    x[13] = d1.x; x[14] = d1.y; x[15] = d1.z; x[16] = d1.w;
    float o;
    mlp_fused<17, 1, 96>(x, wlds, b2, w3, b3, &o);
    he_out[e] = o;
    atomicAdd(agg + d, o);
}

extern "C" void kernel_launch(void* const* d_in, const int* in_sizes, int n_in,
                              void* d_out, int out_size, void* d_ws, size_t ws_size,
                              hipStream_t stream) {
    const int N = N_NODES, E = N_EDGES;
    const float* node_feat = (const float*)d_in[0];
    const float* edge_feat = (const float*)d_in[1];
    const float* edge_dist = (const float*)d_in[2];
    const int* src = (const int*)d_in[3];
    const int* dst = (const int*)d_in[4];
    const float* w_enc1 = (const float*)d_in[5];  const float* b_enc1 = (const float*)d_in[6];
    const float* w_enc2 = (const float*)d_in[7];  const float* b_enc2 = (const float*)d_in[8];
    const float* w_enc3 = (const float*)d_in[9];  const float* b_enc3 = (const float*)d_in[10];
    const float* w_dec1 = (const float*)d_in[11]; const float* b_dec1 = (const float*)d_in[12];
    const float* w_dec2 = (const float*)d_in[13]; const float* b_dec2 = (const float*)d_in[14];
    const float* w_dec3 = (const float*)d_in[15]; const float* b_dec3 = (const float*)d_in[16];
    const float* w_nod1 = (const float*)d_in[17]; const float* b_nod1 = (const float*)d_in[18];
    const float* w_nod2 = (const float*)d_in[19]; const float* b_nod2 = (const float*)d_in[20];
    const float* w_nod3 = (const float*)d_in[21]; const float* b_nod3 = (const float*)d_in[22];
    const float* w_edg1 = (const float*)d_in[23]; const float* b_edg1 = (const float*)d_in[24];
    const float* w_edg2 = (const float*)d_in[25]; const float* b_edg2 = (const float*)d_in[26];
    const float* w_edg3 = (const float*)d_in[27]; const float* b_edg3 = (const float*)d_in[28];

    float* ws = (float*)d_ws;
    float* s      = ws;
    float* hagg1  = ws + N;
    float* agg1   = ws + 9 * N;
    float* agg2   = ws + 10 * N;
    float* hagg2  = ws + 11 * N;
    float* h_enc  = ws + 19 * N;
    float* h_r1   = ws + 27 * N;
    float* h_r2   = ws + 35 * N;
    float* wbuf   = ws + 43 * N;
    float* he1    = wbuf + E;
    float* he2    = he1 + E;
    float* pk_enc = he2 + E;            // 64*80
    float* pk_nod = pk_enc + 64 * 80;   // 64*80
    float* pk_edg = pk_nod + 64 * 80;   // 64*96
    float* pk_dec = pk_edg + 64 * 96;   // 64*80

    // pack weights (runs every call; weights are restored by harness)
    PackArgs pa0{w_enc1, b_enc1, w_enc2, pk_enc, 3, 80};
    PackArgs pa1{w_nod1, b_nod1, w_nod2, pk_nod, 9, 80};
    PackArgs pa2{w_edg1, b_edg1, w_edg2, pk_edg, 17, 96};
    PackArgs pa3{w_dec1, b_dec1, w_dec2, pk_dec, 8, 80};
    pack_kernel<<<4, 64, 0, stream>>>(pa0, pa1, pa2, pa3);

    // zero all accumulators (s, hagg1, agg1, agg2, hagg2)
    zero_kernel<<<2048, 256, 0, stream>>>(ws, 19 * N);
    // encoder
    node_mlp_kernel<3, 0, 8, 80><<<(N + 255) / 256, 256, 0, stream>>>(node_feat, nullptr,
        pk_enc, b_enc2, w_enc3, b_enc3, h_enc, N);
    // edge softmax (no max-subtraction: dist ~ N(0,1), exp can't overflow)
    exp_sum_kernel<<<(E + 255) / 256, 256, 0, stream>>>(edge_dist, dst, s, wbuf, E);
    // normalize + first weighted aggregation
    agg_kernel<true><<<(E * 8 + 255) / 256, 256, 0, stream>>>(wbuf, s, h_enc, src, dst, hagg1, E);
    // round 1
    edge_mlp_kernel<<<(E + 255) / 256, 256, 0, stream>>>(edge_feat, hagg1, src, dst,
        pk_edg, b_edg2, w_edg3, b_edg3, he1, agg1, E);
    node_mlp_kernel<1, 8, 8, 80><<<(N + 255) / 256, 256, 0, stream>>>(agg1, hagg1,
        pk_nod, b_nod2, w_nod3, b_nod3, h_r1, N);
    // round 2
    edge_mlp_kernel<<<(E + 255) / 256, 256, 0, stream>>>(he1, h_r1, src, dst,
        pk_edg, b_edg2, w_edg3, b_edg3, he2, agg2, E);
    node_mlp_kernel<1, 8, 8, 80><<<(N + 255) / 256, 256, 0, stream>>>(agg2, h_r1,
        pk_nod, b_nod2, w_nod3, b_nod3, h_r2, N);
    // second weighted aggregation (reuses normalized wbuf)
    agg_kernel<false><<<(E * 8 + 255) / 256, 256, 0, stream>>>(wbuf, s, h_r2, src, dst, hagg2, E);
    // decoder -> output
    node_mlp_kernel<8, 0, 1, 80><<<(N + 255) / 256, 256, 0, stream>>>(hagg2, nullptr,
        pk_dec, b_dec2, w_dec3, b_dec3, (float*)d_out, N);
}

// Round 9
// 798.440 us; speedup vs baseline: 1.2298x; 1.2298x over previous
//
#include <hip/hip_runtime.h>

#define N_NODES 100000
#define N_EDGES 1600000

typedef __attribute__((ext_vector_type(4))) float f32x4;
typedef __attribute__((ext_vector_type(8))) short bf16x8;

__device__ __forceinline__ unsigned short f2bf(float v) {
    unsigned u = __float_as_uint(v);
    unsigned r = (u + 0x7FFFu + ((u >> 16) & 1u)) >> 16;   // RNE
    return (unsigned short)r;
}
__device__ __forceinline__ float bf2f(unsigned short h) {
    return __uint_as_float(((unsigned)h) << 16);
}

// ---------------- aux kernels (proven R6 state) ----------------------------
__global__ void zero_kernel(float* p, int n) {
    int i = blockIdx.x * blockDim.x + threadIdx.x;
    int stride = gridDim.x * blockDim.x;
    for (; i < n; i += stride) p[i] = 0.f;
}

// exp(d) directly: edge_dist ~ N(0,1) -> no overflow; softmax identical up to ulp.
__global__ void exp_sum_kernel(const float* __restrict__ dist, const int* __restrict__ dst,
                               float* __restrict__ s, float* __restrict__ wbuf, int E) {
    int e = blockIdx.x * blockDim.x + threadIdx.x;
    if (e >= E) return;
    float v = expf(dist[e]);
    wbuf[e] = v;
    atomicAdd(s + dst[e], v);
}

template <bool NORM>
__global__ void agg_kernel(float* wbuf, const float* __restrict__ s,
                           const float* __restrict__ hfeat,
                           const int* __restrict__ src, const int* __restrict__ dst,
                           float* __restrict__ out, int E) {
    int t = blockIdx.x * blockDim.x + threadIdx.x;
    if (t >= E * 8) return;
    int e = t >> 3, c = t & 7;
    float w = wbuf[e];
    int d = dst[e];
    if (NORM) {
        w = w / s[d];
        if (c == 0) wbuf[e] = w;   // 8 lanes read before this lockstep store
    }
    atomicAdd(out + d * 8 + c, w * hfeat[src[e] * 8 + c]);
}

// ---------------- node-MLP weight packing (fp32 path) ----------------------
struct PackArgs { const float *w1, *b1, *w2; float* out; int din, stride; };

__global__ void pack_kernel(PackArgs a0, PackArgs a1, PackArgs a2) {
    PackArgs a = (blockIdx.x == 0) ? a0 : (blockIdx.x == 1) ? a1 : a2;
    int k = threadIdx.x;  // 64 threads
    float* row = a.out + k * a.stride;
    for (int j = 0; j < 64; ++j) row[j] = a.w2[k * 64 + j];
    for (int j = 0; j < a.din; ++j) row[64 + j] = a.w1[j * 64 + k];
    row[64 + a.din] = a.b1[k];
}

// edge weights -> split-bf16, transposed for MFMA A-fragments.
// w1pk[ch][j] (j padded to 32), w2pk[outch][ch]
__global__ void pack_edge_kernel(const float* __restrict__ w1, const float* __restrict__ w2,
                                 unsigned short* __restrict__ w1hi, unsigned short* __restrict__ w1lo,
                                 unsigned short* __restrict__ w2hi, unsigned short* __restrict__ w2lo) {
    int c = threadIdx.x;  // 64 threads
    for (int j = 0; j < 32; ++j) {
        float v = (j < 17) ? w1[j * 64 + c] : 0.f;
        unsigned short hi = f2bf(v);
        w1hi[c * 32 + j] = hi;
        w1lo[c * 32 + j] = f2bf(v - bf2f(hi));
    }
    for (int k = 0; k < 64; ++k) {
        float v = w2[k * 64 + c];
        unsigned short hi = f2bf(v);
        w2hi[c * 64 + k] = hi;
        w2lo[c * 64 + k] = f2bf(v - bf2f(hi));
    }
}

// ---------------- fp32 node MLP (R6 proven): DIN -> 64 -> 64 -> DOUT -------
template <int DIN, int DOUT, int STRIDE>
__device__ __forceinline__ void mlp_fused(
    const float* __restrict__ x, const float* __restrict__ wp,
    const float* __restrict__ b2,
    const float* __restrict__ w3, const float* __restrict__ b3,
    float* __restrict__ out) {
    float h2[64];
#pragma unroll
    for (int j = 0; j < 64; ++j) h2[j] = b2[j];
    for (int k = 0; k < 64; ++k) {
        const float* row = wp + k * STRIDE;
        float a = row[64 + DIN];
#pragma unroll
        for (int j = 0; j < DIN; ++j) a = fmaf(x[j], row[64 + j], a);
        a = fmaxf(a, 0.f);
#pragma unroll
        for (int j = 0; j < 64; ++j) h2[j] = fmaf(a, row[j], h2[j]);
    }
    float acc[DOUT];
#pragma unroll
    for (int o = 0; o < DOUT; ++o) acc[o] = b3[o];
#pragma unroll
    for (int j = 0; j < 64; ++j) {
        float r = fmaxf(h2[j], 0.f);
#pragma unroll
        for (int o = 0; o < DOUT; ++o) acc[o] = fmaf(r, w3[j * DOUT + o], acc[o]);
    }
#pragma unroll
    for (int o = 0; o < DOUT; ++o) out[o] = fmaxf(acc[o], 0.f);
}

template <int CA, int CB, int DOUT, int STRIDE>
__global__ __launch_bounds__(256, 3) void node_mlp_kernel(
    const float* __restrict__ xa, const float* __restrict__ xb,
    const float* __restrict__ wp, const float* __restrict__ b2,
    const float* __restrict__ w3, const float* __restrict__ b3,
    float* __restrict__ out, int n) {
    constexpr int DIN = CA + CB;
    int i = blockIdx.x * 256 + threadIdx.x;
    if (i >= n) return;
    float x[DIN];
#pragma unroll
    for (int k = 0; k < CA; ++k) x[k] = xa[i * CA + k];
    if (CB == 8) {
        float4 v0 = *(const float4*)(xb + i * 8);
        float4 v1 = *(const float4*)(xb + i * 8 + 4);
        x[CA + 0] = v0.x; x[CA + 1] = v0.y; x[CA + 2] = v0.z; x[CA + 3] = v0.w;
        x[CA + 4] = v1.x; x[CA + 5] = v1.y; x[CA + 6] = v1.z; x[CA + 7] = v1.w;
    }
    float o[DOUT];
    mlp_fused<DIN, DOUT, STRIDE>(x, wp, b2, w3, b3, o);
#pragma unroll
    for (int k = 0; k < DOUT; ++k) out[i * DOUT + k] = o[k];
}

// ---------------- split-bf16 MFMA edge MLP: 17 -> 64 -> 64 -> 1 ------------
// 128 threads = 2 waves; each wave owns 64 edges (E = 64*25000 exactly).
// Swapped operands: D[m=ch][n=edge] = W(A) x X^T(B). Both A and B fragments
// are loaded with the same per-lane map (idx=lane&15, k=(lane>>4)*8+i), so
// any consistent k-permutation yields a correct product; C/D map is the
// m89-verified col=lane&15, row=(lane>>4)*4+reg.
// Split product: w*x ~ whi*xhi + whi*xlo + wlo*xhi  (error ~2^-17 rel).
// LDS per wave (18432 B): X region (hi 0..5120, lo 5120..10240, stride 80 B)
// then reused for h1 (hi 0..9216, lo 9216..18432, stride 144 B).
__global__ __launch_bounds__(128, 2) void edge_mlp_mfma_kernel(
    const float* __restrict__ he_in, const float* __restrict__ h,
    const int* __restrict__ src, const int* __restrict__ dst,
    const unsigned short* __restrict__ w1hi, const unsigned short* __restrict__ w1lo,
    const unsigned short* __restrict__ w2hi, const unsigned short* __restrict__ w2lo,
    const float* __restrict__ b1, const float* __restrict__ b2,
    const float* __restrict__ w3, const float* __restrict__ b3,
    float* __restrict__ he_out, float* __restrict__ agg) {
    __shared__ __align__(16) unsigned char smem[2 * 18432];
    const int lane = threadIdx.x & 63, wv = threadIdx.x >> 6;
    unsigned char* W = smem + wv * 18432;
    const int ebase = (blockIdx.x * 2 + wv) * 64;

    // ---- phase 1: gather x[17], split, stage to LDS ----
    {
        int e = ebase + lane;
        float x[32];
        x[0] = he_in[e];
        int sr = src[e], dd = dst[e];
        float4 a0 = *(const float4*)(h + sr * 8);
        float4 a1 = *(const float4*)(h + sr * 8 + 4);
        float4 d0 = *(const float4*)(h + dd * 8);
        float4 d1 = *(const float4*)(h + dd * 8 + 4);
        x[1] = a0.x;  x[2] = a0.y;  x[3] = a0.z;  x[4] = a0.w;
        x[5] = a1.x;  x[6] = a1.y;  x[7] = a1.z;  x[8] = a1.w;
        x[9] = d0.x;  x[10] = d0.y; x[11] = d0.z; x[12] = d0.w;
        x[13] = d1.x; x[14] = d1.y; x[15] = d1.z; x[16] = d1.w;
#pragma unroll
        for (int j = 17; j < 32; ++j) x[j] = 0.f;
        unsigned uh[16], ul[16];
#pragma unroll
        for (int jj = 0; jj < 16; ++jj) {
            unsigned short h0 = f2bf(x[2 * jj]);
            unsigned short h1v = f2bf(x[2 * jj + 1]);
            unsigned short l0 = f2bf(x[2 * jj] - bf2f(h0));
            unsigned short l1 = f2bf(x[2 * jj + 1] - bf2f(h1v));
            uh[jj] = (unsigned)h0 | ((unsigned)h1v << 16);
            ul[jj] = (unsigned)l0 | ((unsigned)l1 << 16);
        }
        uint4* ph = (uint4*)(W + lane * 80);
        uint4* pl = (uint4*)(W + 5120 + lane * 80);
#pragma unroll
        for (int q = 0; q < 4; ++q) {
            ph[q] = make_uint4(uh[4 * q], uh[4 * q + 1], uh[4 * q + 2], uh[4 * q + 3]);
            pl[q] = make_uint4(ul[4 * q], ul[4 * q + 1], ul[4 * q + 2], ul[4 * q + 3]);
        }
    }
    __syncthreads();
    const int row = lane & 15, g = lane >> 4;

    // ---- layer 1: D1[ch][edge] ----
    bf16x8 wa_h[4], wa_l[4];
#pragma unroll
    for (int mt = 0; mt < 4; ++mt) {
        wa_h[mt] = *(const bf16x8*)(w1hi + (16 * mt + row) * 32 + g * 8);
        wa_l[mt] = *(const bf16x8*)(w1lo + (16 * mt + row) * 32 + g * 8);
    }
    bf16x8 xb_h[4], xb_l[4];
#pragma unroll
    for (int nt = 0; nt < 4; ++nt) {
        xb_h[nt] = *(const bf16x8*)(W + (16 * nt + row) * 80 + g * 16);
        xb_l[nt] = *(const bf16x8*)(W + 5120 + (16 * nt + row) * 80 + g * 16);
    }
    f32x4 c1[4][4];
#pragma unroll
    for (int mt = 0; mt < 4; ++mt)
#pragma unroll
        for (int nt = 0; nt < 4; ++nt) {
            f32x4 c = {0.f, 0.f, 0.f, 0.f};
            c = __builtin_amdgcn_mfma_f32_16x16x32_bf16(wa_h[mt], xb_h[nt], c, 0, 0, 0);
            c = __builtin_amdgcn_mfma_f32_16x16x32_bf16(wa_h[mt], xb_l[nt], c, 0, 0, 0);
            c = __builtin_amdgcn_mfma_f32_16x16x32_bf16(wa_l[mt], xb_h[nt], c, 0, 0, 0);
            c1[mt][nt] = c;
        }
    // bias + relu + split + store h1 (overwrites X region; stores depend on
    // mfma results -> transitively ordered after the X reads)
    float4 b1v[4];
#pragma unroll
    for (int mt = 0; mt < 4; ++mt) b1v[mt] = *(const float4*)(b1 + 16 * mt + g * 4);
#pragma unroll
    for (int mt = 0; mt < 4; ++mt)
#pragma unroll
        for (int nt = 0; nt < 4; ++nt) {
            int el = 16 * nt + row;
            int ch0 = 16 * mt + g * 4;
            float v0 = fmaxf(c1[mt][nt].x + b1v[mt].x, 0.f);
            float v1 = fmaxf(c1[mt][nt].y + b1v[mt].y, 0.f);
            float v2 = fmaxf(c1[mt][nt].z + b1v[mt].z, 0.f);
            float v3 = fmaxf(c1[mt][nt].w + b1v[mt].w, 0.f);
            unsigned short h0 = f2bf(v0), h1v = f2bf(v1), h2v = f2bf(v2), h3 = f2bf(v3);
            unsigned hh0 = (unsigned)h0 | ((unsigned)h1v << 16);
            unsigned hh1 = (unsigned)h2v | ((unsigned)h3 << 16);
            unsigned ll0 = (unsigned)f2bf(v0 - bf2f(h0)) | ((unsigned)f2bf(v1 - bf2f(h1v)) << 16);
            unsigned ll1 = (unsigned)f2bf(v2 - bf2f(h2v)) | ((unsigned)f2bf(v3 - bf2f(h3)) << 16);
            *(uint2*)(W + el * 144 + ch0 * 2) = make_uint2(hh0, hh1);
            *(uint2*)(W + 9216 + el * 144 + ch0 * 2) = make_uint2(ll0, ll1);
        }
    __syncthreads();   // also fences layer-2 ds_reads after the h1 writes

    // ---- layer 2 ----
    bf16x8 w2a_h[4][2], w2a_l[4][2];
#pragma unroll
    for (int mt = 0; mt < 4; ++mt)
#pragma unroll
        for (int ks = 0; ks < 2; ++ks) {
            w2a_h[mt][ks] = *(const bf16x8*)(w2hi + (16 * mt + row) * 64 + ks * 32 + g * 8);
            w2a_l[mt][ks] = *(const bf16x8*)(w2lo + (16 * mt + row) * 64 + ks * 32 + g * 8);
        }
    f32x4 c2[4][4];
#pragma unroll
    for (int mt = 0; mt < 4; ++mt)
#pragma unroll
        for (int nt = 0; nt < 4; ++nt) c2[mt][nt] = (f32x4){0.f, 0.f, 0.f, 0.f};
#pragma unroll
    for (int nt = 0; nt < 4; ++nt) {
        bf16x8 hb_h[2], hb_l[2];
#pragma unroll
        for (int ks = 0; ks < 2; ++ks) {
            hb_h[ks] = *(const bf16x8*)(W + (16 * nt + row) * 144 + (ks * 32 + g * 8) * 2);
            hb_l[ks] = *(const bf16x8*)(W + 9216 + (16 * nt + row) * 144 + (ks * 32 + g * 8) * 2);
        }
#pragma unroll
        for (int mt = 0; mt < 4; ++mt)
#pragma unroll
            for (int ks = 0; ks < 2; ++ks) {
                c2[mt][nt] = __builtin_amdgcn_mfma_f32_16x16x32_bf16(w2a_h[mt][ks], hb_h[ks], c2[mt][nt], 0, 0, 0);
                c2[mt][nt] = __builtin_amdgcn_mfma_f32_16x16x32_bf16(w2a_h[mt][ks], hb_l[ks], c2[mt][nt], 0, 0, 0);
                c2[mt][nt] = __builtin_amdgcn_mfma_f32_16x16x32_bf16(w2a_l[mt][ks], hb_h[ks], c2[mt][nt], 0, 0, 0);
            }
    }

    // ---- layer 3 epilogue: out = relu(b3 + sum_ch relu(h2)*w3) ----
    float4 b2v[4], w3v[4];
#pragma unroll
    for (int mt = 0; mt < 4; ++mt) {
        b2v[mt] = *(const float4*)(b2 + 16 * mt + g * 4);
        w3v[mt] = *(const float4*)(w3 + 16 * mt + g * 4);
    }
    float b3s = b3[0];
    float pacc[4];
#pragma unroll
    for (int nt = 0; nt < 4; ++nt) {
        float p = 0.f;
#pragma unroll
        for (int mt = 0; mt < 4; ++mt) {
            p = fmaf(fmaxf(c2[mt][nt].x + b2v[mt].x, 0.f), w3v[mt].x, p);
            p = fmaf(fmaxf(c2[mt][nt].y + b2v[mt].y, 0.f), w3v[mt].y, p);
            p = fmaf(fmaxf(c2[mt][nt].z + b2v[mt].z, 0.f), w3v[mt].z, p);
            p = fmaf(fmaxf(c2[mt][nt].w + b2v[mt].w, 0.f), w3v[mt].w, p);
        }
        p += __shfl_xor(p, 16);
        p += __shfl_xor(p, 32);
        pacc[nt] = p;
    }
    if (lane < 16) {
#pragma unroll
        for (int nt = 0; nt < 4; ++nt) {
            int e2 = ebase + 16 * nt + lane;
            float o = fmaxf(pacc[nt] + b3s, 0.f);
            he_out[e2] = o;
            atomicAdd(agg + dst[e2], o);
        }
    }
}

extern "C" void kernel_launch(void* const* d_in, const int* in_sizes, int n_in,
                              void* d_out, int out_size, void* d_ws, size_t ws_size,
                              hipStream_t stream) {
    const int N = N_NODES, E = N_EDGES;
    const float* node_feat = (const float*)d_in[0];
    const float* edge_feat = (const float*)d_in[1];
    const float* edge_dist = (const float*)d_in[2];
    const int* src = (const int*)d_in[3];
    const int* dst = (const int*)d_in[4];
    const float* w_enc1 = (const float*)d_in[5];  const float* b_enc1 = (const float*)d_in[6];
    const float* w_enc2 = (const float*)d_in[7];  const float* b_enc2 = (const float*)d_in[8];
    const float* w_enc3 = (const float*)d_in[9];  const float* b_enc3 = (const float*)d_in[10];
    const float* w_dec1 = (const float*)d_in[11]; const float* b_dec1 = (const float*)d_in[12];
    const float* w_dec2 = (const float*)d_in[13]; const float* b_dec2 = (const float*)d_in[14];
    const float* w_dec3 = (const float*)d_in[15]; const float* b_dec3 = (const float*)d_in[16];
    const float* w_nod1 = (const float*)d_in[17]; const float* b_nod1 = (const float*)d_in[18];
    const float* w_nod2 = (const float*)d_in[19]; const float* b_nod2 = (const float*)d_in[20];
    const float* w_nod3 = (const float*)d_in[21]; const float* b_nod3 = (const float*)d_in[22];
    const float* w_edg1 = (const float*)d_in[23]; const float* b_edg1 = (const float*)d_in[24];
    const float* w_edg2 = (const float*)d_in[25]; const float* b_edg2 = (const float*)d_in[26];
    const float* w_edg3 = (const float*)d_in[27]; const float* b_edg3 = (const float*)d_in[28];

    float* ws = (float*)d_ws;
    float* s      = ws;
    float* hagg1  = ws + N;
    float* agg1   = ws + 9 * N;
    float* agg2   = ws + 10 * N;
    float* hagg2  = ws + 11 * N;
    float* h_enc  = ws + 19 * N;
    float* h_r1   = ws + 27 * N;
    float* h_r2   = ws + 35 * N;
    float* wbuf   = ws + 43 * N;
    float* he1    = wbuf + E;
    float* he2    = he1 + E;
    float* pk_enc = he2 + E;            // 64*80
    float* pk_nod = pk_enc + 64 * 80;   // 64*80
    float* pk_dec = pk_nod + 64 * 80;   // 64*80
    unsigned short* w1hi = (unsigned short*)(pk_dec + 64 * 80);
    unsigned short* w1lo = w1hi + 64 * 32;
    unsigned short* w2hi = w1lo + 64 * 32;
    unsigned short* w2lo = w2hi + 64 * 64;

    // pack weights (runs every call; inputs restored by harness)
    PackArgs pa0{w_enc1, b_enc1, w_enc2, pk_enc, 3, 80};
    PackArgs pa1{w_nod1, b_nod1, w_nod2, pk_nod, 9, 80};
    PackArgs pa2{w_dec1, b_dec1, w_dec2, pk_dec, 8, 80};
    pack_kernel<<<3, 64, 0, stream>>>(pa0, pa1, pa2);
    pack_edge_kernel<<<1, 64, 0, stream>>>(w_edg1, w_edg2, w1hi, w1lo, w2hi, w2lo);

    // zero accumulators (s, hagg1, agg1, agg2, hagg2)
    zero_kernel<<<2048, 256, 0, stream>>>(ws, 19 * N);
    // encoder
    node_mlp_kernel<3, 0, 8, 80><<<(N + 255) / 256, 256, 0, stream>>>(node_feat, nullptr,
        pk_enc, b_enc2, w_enc3, b_enc3, h_enc, N);
    // edge softmax
    exp_sum_kernel<<<(E + 255) / 256, 256, 0, stream>>>(edge_dist, dst, s, wbuf, E);
    // normalize + first weighted aggregation
    agg_kernel<true><<<(E * 8 + 255) / 256, 256, 0, stream>>>(wbuf, s, h_enc, src, dst, hagg1, E);
    // round 1  (E = 128*12500 exactly)
    edge_mlp_mfma_kernel<<<E / 128, 128, 0, stream>>>(edge_feat, hagg1, src, dst,
        w1hi, w1lo, w2hi, w2lo, b_edg1, b_edg2, w_edg3, b_edg3, he1, agg1);
    node_mlp_kernel<1, 8, 8, 80><<<(N + 255) / 256, 256, 0, stream>>>(agg1, hagg1,
        pk_nod, b_nod2, w_nod3, b_nod3, h_r1, N);
    // round 2
    edge_mlp_mfma_kernel<<<E / 128, 128, 0, stream>>>(he1, h_r1, src, dst,
        w1hi, w1lo, w2hi, w2lo, b_edg1, b_edg2, w_edg3, b_edg3, he2, agg2);
    node_mlp_kernel<1, 8, 8, 80><<<(N + 255) / 256, 256, 0, stream>>>(agg2, h_r1,
        pk_nod, b_nod2, w_nod3, b_nod3, h_r2, N);
    // second weighted aggregation
    agg_kernel<false><<<(E * 8 + 255) / 256, 256, 0, stream>>>(wbuf, s, h_r2, src, dst, hagg2, E);
    // decoder -> output
    node_mlp_kernel<8, 0, 1, 80><<<(N + 255) / 256, 256, 0, stream>>>(hagg2, nullptr,
        pk_dec, b_dec2, w_dec3, b_dec3, (float*)d_out, N);
}

// Round 10
// 721.429 us; speedup vs baseline: 1.3611x; 1.1067x over previous
//
#include <hip/hip_runtime.h>

#define N_NODES 100000
#define N_EDGES 1600000

typedef __attribute__((ext_vector_type(4))) float f32x4;
typedef __attribute__((ext_vector_type(8))) short bf16x8;

__device__ __forceinline__ unsigned short f2bf(float v) {
    unsigned u = __float_as_uint(v);
    unsigned r = (u + 0x7FFFu + ((u >> 16) & 1u)) >> 16;   // RNE
    return (unsigned short)r;
}
__device__ __forceinline__ float bf2f(unsigned short h) {
    return __uint_as_float(((unsigned)h) << 16);
}

// ---------------- aux kernels (proven R6 state) ----------------------------
__global__ void zero_kernel(float* p, int n) {
    int i = blockIdx.x * blockDim.x + threadIdx.x;
    int stride = gridDim.x * blockDim.x;
    for (; i < n; i += stride) p[i] = 0.f;
}

__global__ void exp_sum_kernel(const float* __restrict__ dist, const int* __restrict__ dst,
                               float* __restrict__ s, float* __restrict__ wbuf, int E) {
    int e = blockIdx.x * blockDim.x + threadIdx.x;
    if (e >= E) return;
    float v = expf(dist[e]);
    wbuf[e] = v;
    atomicAdd(s + dst[e], v);
}

template <bool NORM>
__global__ void agg_kernel(float* wbuf, const float* __restrict__ s,
                           const float* __restrict__ hfeat,
                           const int* __restrict__ src, const int* __restrict__ dst,
                           float* __restrict__ out, int E) {
    int t = blockIdx.x * blockDim.x + threadIdx.x;
    if (t >= E * 8) return;
    int e = t >> 3, c = t & 7;
    float w = wbuf[e];
    int d = dst[e];
    if (NORM) {
        w = w / s[d];
        if (c == 0) wbuf[e] = w;   // 8 lanes read before this lockstep store
    }
    atomicAdd(out + d * 8 + c, w * hfeat[src[e] * 8 + c]);
}

// ---------------- node-MLP weight packing (fp32 path) ----------------------
struct PackArgs { const float *w1, *b1, *w2; float* out; int din, stride; };

__global__ void pack_kernel(PackArgs a0, PackArgs a1, PackArgs a2) {
    PackArgs a = (blockIdx.x == 0) ? a0 : (blockIdx.x == 1) ? a1 : a2;
    int k = threadIdx.x;  // 64 threads
    float* row = a.out + k * a.stride;
    for (int j = 0; j < 64; ++j) row[j] = a.w2[k * 64 + j];
    for (int j = 0; j < a.din; ++j) row[64 + j] = a.w1[j * 64 + k];
    row[64 + a.din] = a.b1[k];
}

// edge weights -> split-bf16.
// w1: [ch][j(32-padded)] standard k-map (kappa(g,i)=g*8+i).
// w2: kappa'-order so layer-2 A matches the in-register layer-1 C layout:
//   lane(row,g), tile mt, k-half ks, element i -> outch=16mt+row,
//   ch = ks*32 + 16*(i>>2) + 4g + (i&3).
__global__ void pack_edge_kernel(const float* __restrict__ w1, const float* __restrict__ w2,
                                 unsigned short* __restrict__ w1hi, unsigned short* __restrict__ w1lo,
                                 unsigned short* __restrict__ w2hi, unsigned short* __restrict__ w2lo) {
    int c = threadIdx.x;  // 64 threads; c = ch (w1) / outch (w2)
    for (int j = 0; j < 32; ++j) {
        float v = (j < 17) ? w1[j * 64 + c] : 0.f;
        unsigned short hi = f2bf(v);
        w1hi[c * 32 + j] = hi;
        w1lo[c * 32 + j] = f2bf(v - bf2f(hi));
    }
    int mt = c >> 4, row = c & 15;
    for (int ch = 0; ch < 64; ++ch) {
        int ks = ch >> 5, r5 = ch & 31;
        int i = ((r5 >> 4) << 2) | (r5 & 3);
        int g = (r5 >> 2) & 3;
        int dstIdx = (((mt * 2 + ks) * 16 + row) * 4 + g) * 8 + i;
        float v = w2[ch * 64 + c];
        unsigned short hi = f2bf(v);
        w2hi[dstIdx] = hi;
        w2lo[dstIdx] = f2bf(v - bf2f(hi));
    }
}

// ---------------- fp32 node MLP (R6 proven): DIN -> 64 -> 64 -> DOUT -------
template <int DIN, int DOUT, int STRIDE>
__device__ __forceinline__ void mlp_fused(
    const float* __restrict__ x, const float* __restrict__ wp,
    const float* __restrict__ b2,
    const float* __restrict__ w3, const float* __restrict__ b3,
    float* __restrict__ out) {
    float h2[64];
#pragma unroll
    for (int j = 0; j < 64; ++j) h2[j] = b2[j];
    for (int k = 0; k < 64; ++k) {
        const float* row = wp + k * STRIDE;
        float a = row[64 + DIN];
#pragma unroll
        for (int j = 0; j < DIN; ++j) a = fmaf(x[j], row[64 + j], a);
        a = fmaxf(a, 0.f);
#pragma unroll
        for (int j = 0; j < 64; ++j) h2[j] = fmaf(a, row[j], h2[j]);
    }
    float acc[DOUT];
#pragma unroll
    for (int o = 0; o < DOUT; ++o) acc[o] = b3[o];
#pragma unroll
    for (int j = 0; j < 64; ++j) {
        float r = fmaxf(h2[j], 0.f);
#pragma unroll
        for (int o = 0; o < DOUT; ++o) acc[o] = fmaf(r, w3[j * DOUT + o], acc[o]);
    }
#pragma unroll
    for (int o = 0; o < DOUT; ++o) out[o] = fmaxf(acc[o], 0.f);
}

template <int CA, int CB, int DOUT, int STRIDE>
__global__ __launch_bounds__(256, 3) void node_mlp_kernel(
    const float* __restrict__ xa, const float* __restrict__ xb,
    const float* __restrict__ wp, const float* __restrict__ b2,
    const float* __restrict__ w3, const float* __restrict__ b3,
    float* __restrict__ out, int n) {
    constexpr int DIN = CA + CB;
    int i = blockIdx.x * 256 + threadIdx.x;
    if (i >= n) return;
    float x[DIN];
#pragma unroll
    for (int k = 0; k < CA; ++k) x[k] = xa[i * CA + k];
    if (CB == 8) {
        float4 v0 = *(const float4*)(xb + i * 8);
        float4 v1 = *(const float4*)(xb + i * 8 + 4);
        x[CA + 0] = v0.x; x[CA + 1] = v0.y; x[CA + 2] = v0.z; x[CA + 3] = v0.w;
        x[CA + 4] = v1.x; x[CA + 5] = v1.y; x[CA + 6] = v1.z; x[CA + 7] = v1.w;
    }
    float o[DOUT];
    mlp_fused<DIN, DOUT, STRIDE>(x, wp, b2, w3, b3, o);
#pragma unroll
    for (int k = 0; k < DOUT; ++k) out[i * DOUT + k] = o[k];
}

// ---------------- split-bf16 MFMA edge MLP: 17 -> 64 -> 64 -> 1 ------------
// 2 waves/block, 64 edges/wave. Layer-1: D1[ch][edge] = W1 x X^T (X staged in
// LDS, 10240 B/wave). Layer-2 consumes layer-1 accumulators DIRECTLY from
// registers: w2 is pre-packed in the kappa' order matching the C-layout, so
// no h1 LDS round-trip, no second barrier. Split product per layer:
// hi*hi + hi*lo + lo*hi. Accumulation order per (mt,nt) identical to R9.
__global__ __launch_bounds__(128, 2) void edge_mlp_mfma_kernel(
    const float* __restrict__ he_in, const float* __restrict__ h,
    const int* __restrict__ src, const int* __restrict__ dst,
    const unsigned short* __restrict__ w1hi, const unsigned short* __restrict__ w1lo,
    const unsigned short* __restrict__ w2hi, const unsigned short* __restrict__ w2lo,
    const float* __restrict__ b1, const float* __restrict__ b2,
    const float* __restrict__ w3, const float* __restrict__ b3,
    float* __restrict__ he_out, float* __restrict__ agg) {
    __shared__ __align__(16) unsigned char smem[2 * 10240];
    const int lane = threadIdx.x & 63, wv = threadIdx.x >> 6;
    unsigned char* W = smem + wv * 10240;
    const int ebase = (blockIdx.x * 2 + wv) * 64;

    // ---- phase 1: gather x[17], split, stage to LDS (hi @0, lo @5120) ----
    {
        int e = ebase + lane;
        float x[32];
        x[0] = he_in[e];
        int sr = src[e], dd = dst[e];
        float4 a0 = *(const float4*)(h + sr * 8);
        float4 a1 = *(const float4*)(h + sr * 8 + 4);
        float4 d0 = *(const float4*)(h + dd * 8);
        float4 d1 = *(const float4*)(h + dd * 8 + 4);
        x[1] = a0.x;  x[2] = a0.y;  x[3] = a0.z;  x[4] = a0.w;
        x[5] = a1.x;  x[6] = a1.y;  x[7] = a1.z;  x[8] = a1.w;
        x[9] = d0.x;  x[10] = d0.y; x[11] = d0.z; x[12] = d0.w;
        x[13] = d1.x; x[14] = d1.y; x[15] = d1.z; x[16] = d1.w;
#pragma unroll
        for (int j = 17; j < 32; ++j) x[j] = 0.f;
        unsigned uh[16], ul[16];
#pragma unroll
        for (int jj = 0; jj < 16; ++jj) {
            unsigned short h0 = f2bf(x[2 * jj]);
            unsigned short h1v = f2bf(x[2 * jj + 1]);
            unsigned short l0 = f2bf(x[2 * jj] - bf2f(h0));
            unsigned short l1 = f2bf(x[2 * jj + 1] - bf2f(h1v));
            uh[jj] = (unsigned)h0 | ((unsigned)h1v << 16);
            ul[jj] = (unsigned)l0 | ((unsigned)l1 << 16);
        }
        uint4* ph = (uint4*)(W + lane * 80);
        uint4* pl = (uint4*)(W + 5120 + lane * 80);
#pragma unroll
        for (int q = 0; q < 4; ++q) {
            ph[q] = make_uint4(uh[4 * q], uh[4 * q + 1], uh[4 * q + 2], uh[4 * q + 3]);
            pl[q] = make_uint4(ul[4 * q], ul[4 * q + 1], ul[4 * q + 2], ul[4 * q + 3]);
        }
    }
    __syncthreads();
    const int row = lane & 15, g = lane >> 4;

    // ---- layer 1: D1[ch][edge] ----
    bf16x8 wa_h[4], wa_l[4];
#pragma unroll
    for (int mt = 0; mt < 4; ++mt) {
        wa_h[mt] = *(const bf16x8*)(w1hi + (16 * mt + row) * 32 + g * 8);
        wa_l[mt] = *(const bf16x8*)(w1lo + (16 * mt + row) * 32 + g * 8);
    }
    bf16x8 xb_h[4], xb_l[4];
#pragma unroll
    for (int nt = 0; nt < 4; ++nt) {
        xb_h[nt] = *(const bf16x8*)(W + (16 * nt + row) * 80 + g * 16);
        xb_l[nt] = *(const bf16x8*)(W + 5120 + (16 * nt + row) * 80 + g * 16);
    }
    f32x4 c1[4][4];
#pragma unroll
    for (int mt = 0; mt < 4; ++mt)
#pragma unroll
        for (int nt = 0; nt < 4; ++nt) {
            f32x4 c = {0.f, 0.f, 0.f, 0.f};
            c = __builtin_amdgcn_mfma_f32_16x16x32_bf16(wa_h[mt], xb_h[nt], c, 0, 0, 0);
            c = __builtin_amdgcn_mfma_f32_16x16x32_bf16(wa_h[mt], xb_l[nt], c, 0, 0, 0);
            c = __builtin_amdgcn_mfma_f32_16x16x32_bf16(wa_l[mt], xb_h[nt], c, 0, 0, 0);
            c1[mt][nt] = c;
        }

    // ---- bias+relu+split IN REGISTERS -> layer-2 B fragments (kappa') ----
    float4 b1v[4];
#pragma unroll
    for (int mt = 0; mt < 4; ++mt) b1v[mt] = *(const float4*)(b1 + 16 * mt + g * 4);
    bf16x8 pb_h[4][2], pb_l[4][2];
#pragma unroll
    for (int nt = 0; nt < 4; ++nt)
#pragma unroll
        for (int ks = 0; ks < 2; ++ks) {
            float v0 = fmaxf(c1[2 * ks][nt].x + b1v[2 * ks].x, 0.f);
            float v1 = fmaxf(c1[2 * ks][nt].y + b1v[2 * ks].y, 0.f);
            float v2 = fmaxf(c1[2 * ks][nt].z + b1v[2 * ks].z, 0.f);
            float v3 = fmaxf(c1[2 * ks][nt].w + b1v[2 * ks].w, 0.f);
            float v4 = fmaxf(c1[2 * ks + 1][nt].x + b1v[2 * ks + 1].x, 0.f);
            float v5 = fmaxf(c1[2 * ks + 1][nt].y + b1v[2 * ks + 1].y, 0.f);
            float v6 = fmaxf(c1[2 * ks + 1][nt].z + b1v[2 * ks + 1].z, 0.f);
            float v7 = fmaxf(c1[2 * ks + 1][nt].w + b1v[2 * ks + 1].w, 0.f);
            unsigned short h0 = f2bf(v0), h1v = f2bf(v1), h2v = f2bf(v2), h3 = f2bf(v3);
            unsigned short h4 = f2bf(v4), h5 = f2bf(v5), h6 = f2bf(v6), h7 = f2bf(v7);
            bf16x8 ph, pl;
            ph[0] = h0; ph[1] = h1v; ph[2] = h2v; ph[3] = h3;
            ph[4] = h4; ph[5] = h5;  ph[6] = h6;  ph[7] = h7;
            pl[0] = f2bf(v0 - bf2f(h0)); pl[1] = f2bf(v1 - bf2f(h1v));
            pl[2] = f2bf(v2 - bf2f(h2v)); pl[3] = f2bf(v3 - bf2f(h3));
            pl[4] = f2bf(v4 - bf2f(h4)); pl[5] = f2bf(v5 - bf2f(h5));
            pl[6] = f2bf(v6 - bf2f(h6)); pl[7] = f2bf(v7 - bf2f(h7));
            pb_h[nt][ks] = ph;
            pb_l[nt][ks] = pl;
        }

    // ---- layer 2: D2[outch][edge], A = w2 (kappa'-packed), B = pb ----
    f32x4 c2[4][4];
#pragma unroll
    for (int mt = 0; mt < 4; ++mt)
#pragma unroll
        for (int nt = 0; nt < 4; ++nt) c2[mt][nt] = (f32x4){0.f, 0.f, 0.f, 0.f};
#pragma unroll
    for (int mt = 0; mt < 4; ++mt) {
        bf16x8 w2a_h[2], w2a_l[2];
#pragma unroll
        for (int ks = 0; ks < 2; ++ks) {
            int off = (((mt * 2 + ks) * 16 + row) * 4 + g) * 8;
            w2a_h[ks] = *(const bf16x8*)(w2hi + off);
            w2a_l[ks] = *(const bf16x8*)(w2lo + off);
        }
#pragma unroll
        for (int nt = 0; nt < 4; ++nt)
#pragma unroll
            for (int ks = 0; ks < 2; ++ks) {
                c2[mt][nt] = __builtin_amdgcn_mfma_f32_16x16x32_bf16(w2a_h[ks], pb_h[nt][ks], c2[mt][nt], 0, 0, 0);
                c2[mt][nt] = __builtin_amdgcn_mfma_f32_16x16x32_bf16(w2a_h[ks], pb_l[nt][ks], c2[mt][nt], 0, 0, 0);
                c2[mt][nt] = __builtin_amdgcn_mfma_f32_16x16x32_bf16(w2a_l[ks], pb_h[nt][ks], c2[mt][nt], 0, 0, 0);
            }
    }

    // ---- layer 3 epilogue: out = relu(b3 + sum_ch relu(h2)*w3) ----
    float4 b2v[4], w3v[4];
#pragma unroll
    for (int mt = 0; mt < 4; ++mt) {
        b2v[mt] = *(const float4*)(b2 + 16 * mt + g * 4);
        w3v[mt] = *(const float4*)(w3 + 16 * mt + g * 4);
    }
    float b3s = b3[0];
    float pacc[4];
#pragma unroll
    for (int nt = 0; nt < 4; ++nt) {
        float p = 0.f;
#pragma unroll
        for (int mt = 0; mt < 4; ++mt) {
            p = fmaf(fmaxf(c2[mt][nt].x + b2v[mt].x, 0.f), w3v[mt].x, p);
            p = fmaf(fmaxf(c2[mt][nt].y + b2v[mt].y, 0.f), w3v[mt].y, p);
            p = fmaf(fmaxf(c2[mt][nt].z + b2v[mt].z, 0.f), w3v[mt].z, p);
            p = fmaf(fmaxf(c2[mt][nt].w + b2v[mt].w, 0.f), w3v[mt].w, p);
        }
        p += __shfl_xor(p, 16);
        p += __shfl_xor(p, 32);
        pacc[nt] = p;
    }
    if (lane < 16) {
#pragma unroll
        for (int nt = 0; nt < 4; ++nt) {
            int e2 = ebase + 16 * nt + lane;
            float o = fmaxf(pacc[nt] + b3s, 0.f);
            he_out[e2] = o;
            atomicAdd(agg + dst[e2], o);
        }
    }
}

extern "C" void kernel_launch(void* const* d_in, const int* in_sizes, int n_in,
                              void* d_out, int out_size, void* d_ws, size_t ws_size,
                              hipStream_t stream) {
    const int N = N_NODES, E = N_EDGES;
    const float* node_feat = (const float*)d_in[0];
    const float* edge_feat = (const float*)d_in[1];
    const float* edge_dist = (const float*)d_in[2];
    const int* src = (const int*)d_in[3];
    const int* dst = (const int*)d_in[4];
    const float* w_enc1 = (const float*)d_in[5];  const float* b_enc1 = (const float*)d_in[6];
    const float* w_enc2 = (const float*)d_in[7];  const float* b_enc2 = (const float*)d_in[8];
    const float* w_enc3 = (const float*)d_in[9];  const float* b_enc3 = (const float*)d_in[10];
    const float* w_dec1 = (const float*)d_in[11]; const float* b_dec1 = (const float*)d_in[12];
    const float* w_dec2 = (const float*)d_in[13]; const float* b_dec2 = (const float*)d_in[14];
    const float* w_dec3 = (const float*)d_in[15]; const float* b_dec3 = (const float*)d_in[16];
    const float* w_nod1 = (const float*)d_in[17]; const float* b_nod1 = (const float*)d_in[18];
    const float* w_nod2 = (const float*)d_in[19]; const float* b_nod2 = (const float*)d_in[20];
    const float* w_nod3 = (const float*)d_in[21]; const float* b_nod3 = (const float*)d_in[22];
    const float* w_edg1 = (const float*)d_in[23]; const float* b_edg1 = (const float*)d_in[24];
    const float* w_edg2 = (const float*)d_in[25]; const float* b_edg2 = (const float*)d_in[26];
    const float* w_edg3 = (const float*)d_in[27]; const float* b_edg3 = (const float*)d_in[28];

    float* ws = (float*)d_ws;
    float* s      = ws;
    float* hagg1  = ws + N;
    float* agg1   = ws + 9 * N;
    float* agg2   = ws + 10 * N;
    float* hagg2  = ws + 11 * N;
    float* h_enc  = ws + 19 * N;
    float* h_r1   = ws + 27 * N;
    float* h_r2   = ws + 35 * N;
    float* wbuf   = ws + 43 * N;
    float* he1    = wbuf + E;
    float* he2    = he1 + E;
    float* pk_enc = he2 + E;            // 64*80
    float* pk_nod = pk_enc + 64 * 80;   // 64*80
    float* pk_dec = pk_nod + 64 * 80;   // 64*80
    unsigned short* w1hi = (unsigned short*)(pk_dec + 64 * 80);
    unsigned short* w1lo = w1hi + 64 * 32;
    unsigned short* w2hi = w1lo + 64 * 32;
    unsigned short* w2lo = w2hi + 64 * 64;

    // pack weights (runs every call; inputs restored by harness)
    PackArgs pa0{w_enc1, b_enc1, w_enc2, pk_enc, 3, 80};
    PackArgs pa1{w_nod1, b_nod1, w_nod2, pk_nod, 9, 80};
    PackArgs pa2{w_dec1, b_dec1, w_dec2, pk_dec, 8, 80};
    pack_kernel<<<3, 64, 0, stream>>>(pa0, pa1, pa2);
    pack_edge_kernel<<<1, 64, 0, stream>>>(w_edg1, w_edg2, w1hi, w1lo, w2hi, w2lo);

    // zero accumulators (s, hagg1, agg1, agg2, hagg2)
    zero_kernel<<<2048, 256, 0, stream>>>(ws, 19 * N);
    // encoder
    node_mlp_kernel<3, 0, 8, 80><<<(N + 255) / 256, 256, 0, stream>>>(node_feat, nullptr,
        pk_enc, b_enc2, w_enc3, b_enc3, h_enc, N);
    // edge softmax
    exp_sum_kernel<<<(E + 255) / 256, 256, 0, stream>>>(edge_dist, dst, s, wbuf, E);
    // normalize + first weighted aggregation
    agg_kernel<true><<<(E * 8 + 255) / 256, 256, 0, stream>>>(wbuf, s, h_enc, src, dst, hagg1, E);
    // round 1  (E = 128*12500 exactly)
    edge_mlp_mfma_kernel<<<E / 128, 128, 0, stream>>>(edge_feat, hagg1, src, dst,
        w1hi, w1lo, w2hi, w2lo, b_edg1, b_edg2, w_edg3, b_edg3, he1, agg1);
    node_mlp_kernel<1, 8, 8, 80><<<(N + 255) / 256, 256, 0, stream>>>(agg1, hagg1,
        pk_nod, b_nod2, w_nod3, b_nod3, h_r1, N);
    // round 2
    edge_mlp_mfma_kernel<<<E / 128, 128, 0, stream>>>(he1, h_r1, src, dst,
        w1hi, w1lo, w2hi, w2lo, b_edg1, b_edg2, w_edg3, b_edg3, he2, agg2);
    node_mlp_kernel<1, 8, 8, 80><<<(N + 255) / 256, 256, 0, stream>>>(agg2, h_r1,
        pk_nod, b_nod2, w_nod3, b_nod3, h_r2, N);
    // second weighted aggregation
    agg_kernel<false><<<(E * 8 + 255) / 256, 256, 0, stream>>>(wbuf, s, h_r2, src, dst, hagg2, E);
    // decoder -> output
    node_mlp_kernel<8, 0, 1, 80><<<(N + 255) / 256, 256, 0, stream>>>(hagg2, nullptr,
        pk_dec, b_dec2, w_dec3, b_dec3, (float*)d_out, N);
}